// Round 8
// baseline (265.025 us; speedup 1.0000x reference)
//
#include <hip/hip_runtime.h>
#include <math.h>

// ---------------- workspace layout (float offsets) ----------------
#define WS_P  0         // P[4][128*128]  pair products
#define WS_Q0 65536     // Wa0..3 product
#define WS_Q1 81920     // Wa4..7 product
#define WS_R  98304     // Wa4*Wa5*Wa6
#define WS_WT 114688    // W~[8][128*128]
#define WS_WU 245760    // WU[k][i*128+h] = W~_i[h][k]   (128 x 1024)
#define WS_ZT 376832    // Z[c*128 + k'] = M_i[h][k'], c=i*128+h  (1024 x 128)
#define WS_Z0 507904    // z0[128]
#define WS_U  524288    // U/S [8192][1024]  (u then overwritten by s)
#define WS_PO 8912896   // partials kc=1..3: 3 x 8192x128

struct MMJob { const float* A; const float* B; float* C; float* wu; };
struct MMArgs { MMJob j[8]; };

// ---- DPP cross-lane (VALU pipe, not DS): xor1/xor2 = quad_perm, xor8 = row_ror:8
__device__ __forceinline__ float dpp_xor1(float x) {
  return __int_as_float(__builtin_amdgcn_update_dpp(0, __float_as_int(x), 0xB1, 0xF, 0xF, false));
}
__device__ __forceinline__ float dpp_xor2(float x) {
  return __int_as_float(__builtin_amdgcn_update_dpp(0, __float_as_int(x), 0x4E, 0xF, 0xF, false));
}
__device__ __forceinline__ float dpp_xor8(float x) {
  return __int_as_float(__builtin_amdgcn_update_dpp(0, __float_as_int(x), 0x128, 0xF, 0xF, false));
}
__device__ __forceinline__ float readlane_f(float v, int n) {
  return __int_as_float(__builtin_amdgcn_readlane(__float_as_int(v), n));
}

// ---- 128x128 matmul job (C = A@B; A==nullptr -> copy B). wu = transposed store.
__device__ void mm128_job(const MMJob J, const int tile, const int t, float* Al) {
  const int col = t & 127;
  const int rg = t >> 7;
  if (J.A == nullptr) {
    for (int rr = 0; rr < 16; ++rr) {
      const int r = tile * 32 + rg * 16 + rr;
      const float v = J.B[r * 128 + col];
      if (J.C) J.C[r * 128 + col] = v;
      if (J.wu) J.wu[col * 1024 + r] = v;
    }
    return;
  }
  for (int jj = 0; jj < 16; ++jj) {
    const int idx = t + jj * 256;
    Al[idx] = J.A[tile * 32 * 128 + idx];
  }
  __syncthreads();
  float acc[16];
#pragma unroll
  for (int rr = 0; rr < 16; ++rr) acc[rr] = 0.f;
  for (int h = 0; h < 128; ++h) {
    const float bv = J.B[h * 128 + col];
#pragma unroll
    for (int rr = 0; rr < 16; ++rr)
      acc[rr] = fmaf(Al[(rg * 16 + rr) * 128 + h], bv, acc[rr]);
  }
#pragma unroll
  for (int rr = 0; rr < 16; ++rr) {
    const int r = tile * 32 + rg * 16 + rr;
    if (J.C) J.C[r * 128 + col] = acc[rr];
    if (J.wu) J.wu[col * 1024 + r] = acc[rr];
  }
}

// ---- K1: level-1 pair products (blocks 0..15) + bias chain/z0 (block 16)
__global__ __launch_bounds__(256) void k1_setup(MMArgs args,
    const float* __restrict__ Wa, const float* __restrict__ ba,
    const float* __restrict__ Wo, const float* __restrict__ bo,
    float* __restrict__ z0) {
  __shared__ float smem[4096];
  const int t = threadIdx.x;
  if (blockIdx.x < 16) {
    mm128_job(args.j[blockIdx.x >> 2], blockIdx.x & 3, t, smem);
    return;
  }
  float* bt = smem;            // [8][128]
  float* zpart = smem + 1024;  // [2][128]
  if (t < 128) bt[t] = ba[t];
  __syncthreads();
  for (int i = 1; i < 8; ++i) {
    if (t < 128) {
      float v = ba[i * 128 + t];
      for (int h = 0; h < 128; ++h)
        v = fmaf(bt[(i - 1) * 128 + h], Wa[i * 16384 + h * 128 + t], v);
      bt[i * 128 + t] = v;
    }
    __syncthreads();
  }
  const int col = t & 127, half = t >> 7;
  float z = half ? 0.f : bo[col];
  for (int i = half * 4; i < half * 4 + 4; ++i)
    for (int h = 0; h < 128; ++h)
      z = fmaf(bt[i * 128 + h], Wo[(i * 128 + h) * 128 + col], z);
  zpart[half * 128 + col] = z;
  __syncthreads();
  if (t < 128) z0[t] = zpart[t] + zpart[128 + t];
}

__global__ __launch_bounds__(256) void mm128_jobs(MMArgs args) {
  __shared__ float smem[4096];
  mm128_job(args.j[blockIdx.x >> 2], blockIdx.x & 3, threadIdx.x, smem);
}

// ---- gemm_U: U[b][c] = sum_k V[b][k] WU[k][c]; 128 rows x 128 cols per block
__device__ void gemm_U_dev(const float* __restrict__ V, const float* __restrict__ WU,
                           float* __restrict__ U, const int bid, const int t, float* Vl) {
  const int rt = bid >> 3;
  const int ct = bid & 7;
  const int cg = t & 7;
  const int rg = t >> 3;
  const int r0 = rt * 128;
  float4 acc[4][4];
#pragma unroll
  for (int a = 0; a < 4; ++a)
#pragma unroll
    for (int c = 0; c < 4; ++c) acc[a][c] = make_float4(0.f, 0.f, 0.f, 0.f);
  for (int kc = 0; kc < 4; ++kc) {
    __syncthreads();
    {
      const int srow = t >> 3, k8 = t & 7;
#pragma unroll
      for (int pp = 0; pp < 4; ++pp) {
        const int rr = pp * 32 + srow;
        *(float4*)&Vl[rr * 33 + k8 * 4] =
            *(const float4*)&V[(size_t)(r0 + rr) * 128 + kc * 32 + k8 * 4];
      }
    }
    __syncthreads();
#pragma unroll 4
    for (int kk = 0; kk < 32; ++kk) {
      const float* wrow = WU + (size_t)(kc * 32 + kk) * 1024 + ct * 128 + cg * 16;
      const float4 w0 = *(const float4*)(wrow + 0);
      const float4 w1 = *(const float4*)(wrow + 4);
      const float4 w2 = *(const float4*)(wrow + 8);
      const float4 w3 = *(const float4*)(wrow + 12);
#pragma unroll
      for (int r = 0; r < 4; ++r) {
        const float s = Vl[(rg * 4 + r) * 33 + kk];
        acc[r][0].x = fmaf(s, w0.x, acc[r][0].x); acc[r][0].y = fmaf(s, w0.y, acc[r][0].y);
        acc[r][0].z = fmaf(s, w0.z, acc[r][0].z); acc[r][0].w = fmaf(s, w0.w, acc[r][0].w);
        acc[r][1].x = fmaf(s, w1.x, acc[r][1].x); acc[r][1].y = fmaf(s, w1.y, acc[r][1].y);
        acc[r][1].z = fmaf(s, w1.z, acc[r][1].z); acc[r][1].w = fmaf(s, w1.w, acc[r][1].w);
        acc[r][2].x = fmaf(s, w2.x, acc[r][2].x); acc[r][2].y = fmaf(s, w2.y, acc[r][2].y);
        acc[r][2].z = fmaf(s, w2.z, acc[r][2].z); acc[r][2].w = fmaf(s, w2.w, acc[r][2].w);
        acc[r][3].x = fmaf(s, w3.x, acc[r][3].x); acc[r][3].y = fmaf(s, w3.y, acc[r][3].y);
        acc[r][3].z = fmaf(s, w3.z, acc[r][3].z); acc[r][3].w = fmaf(s, w3.w, acc[r][3].w);
      }
    }
  }
#pragma unroll
  for (int r = 0; r < 4; ++r) {
    float* urow = U + (size_t)(r0 + rg * 4 + r) * 1024 + ct * 128 + cg * 16;
    *(float4*)(urow + 0) = acc[r][0];
    *(float4*)(urow + 4) = acc[r][1];
    *(float4*)(urow + 8) = acc[r][2];
    *(float4*)(urow + 12) = acc[r][3];
  }
}

// ---- K4: level-4 ZT jobs (0..31) + gemm_U (32..543)
__global__ __launch_bounds__(256) void k4_combo(MMArgs args,
    const float* __restrict__ V, const float* __restrict__ WU, float* __restrict__ U) {
  __shared__ float smem[4224];
  const int bid = blockIdx.x;
  if (bid < 32) mm128_job(args.j[bid >> 2], bid & 3, threadIdx.x, smem);
  else gemm_U_dev(V, WU, U, bid - 32, threadIdx.x, smem);
}

// ---- attn: DS-minimized body (R7), 4 sequential batches per block (grid 2048)
// to amortize dispatch overhead. Plain rolled loop, no register double-buffer.
#define ATTN_NB 4

__global__ __launch_bounds__(256, 4) void attn_main_k(
    const float* __restrict__ query, const float* __restrict__ value,
    float* __restrict__ U) {
  __shared__ float smem[4948];   // epart 65*68=4420 (spart[4][1024] overlays) + sct 8*66
  float* sct = smem + 4420;
  const int t = threadIdx.x;
  const int w = t >> 6;
  const int l = t & 63;

  const int sel1 = l & 1, sel2 = (l >> 1) & 1, sel8 = (l >> 3) & 1;
  const int g = ((l >> 2) & 1) | (((l >> 4) & 1) << 1) | (((l >> 5) & 1) << 2);
  const int myhead = 4 * sel1 + 2 * sel2 + sel8;
  const int ebase = myhead * 8 + g;  // 0..63, bijective over lanes

#pragma unroll 1
  for (int j = 0; j < ATTN_NB; ++j) {
    const int b = blockIdx.x * ATTN_NB + j;

    float2 u2[8];
    {
      const float* ub = U + (size_t)b * 1024 + 2 * l;
#pragma unroll
      for (int i = 0; i < 8; ++i) u2[i] = *(const float2*)(ub + i * 128);
    }
    float2 q2[16];
    {
      const float* qb = query + (size_t)b * 8192 + (size_t)(w * 16) * 128 + 2 * l;
#pragma unroll
      for (int r = 0; r < 16; ++r) q2[r] = *(const float2*)(qb + r * 128);
    }
    const float2 v2 = *(const float2*)(value + (size_t)b * 128 + 2 * l);

    auto epass = [&](const float2 qv, const int n) {
      float p[8];
#pragma unroll
      for (int i = 0; i < 8; ++i) p[i] = fmaf(qv.y, u2[i].y, qv.x * u2[i].x);
      float a4[4];
#pragma unroll
      for (int i = 0; i < 4; ++i) {
        const float yours = sel1 ? p[i] : p[i + 4];
        const float mine = sel1 ? p[i + 4] : p[i];
        a4[i] = mine + dpp_xor1(yours);
      }
      float a2v[2];
#pragma unroll
      for (int i = 0; i < 2; ++i) {
        const float yours = sel2 ? a4[i] : a4[i + 2];
        const float mine = sel2 ? a4[i + 2] : a4[i];
        a2v[i] = mine + dpp_xor2(yours);
      }
      const float yours = sel8 ? a2v[0] : a2v[1];
      const float mine = sel8 ? a2v[1] : a2v[0];
      smem[n * 68 + ebase] = mine + dpp_xor8(yours);
    };
#pragma unroll
    for (int r = 0; r < 16; ++r) epass(q2[r], 16 * w + r);
    if (w == 0) epass(v2, 64);
    __syncthreads();

    // softmax: wave w -> heads 2w, 2w+1; lane l -> row n=l; sums 8 g-partials.
#pragma unroll
    for (int ii = 0; ii < 2; ++ii) {
      const int i = 2 * w + ii;
      const float4 e0 = *(const float4*)&smem[l * 68 + i * 8];
      const float4 e1 = *(const float4*)&smem[l * 68 + i * 8 + 4];
      const float4 f0 = *(const float4*)&smem[64 * 68 + i * 8];
      const float4 f1 = *(const float4*)&smem[64 * 68 + i * 8 + 4];
      const float x = ((e0.x + e0.y) + (e0.z + e0.w)) + ((e1.x + e1.y) + (e1.z + e1.w));
      const float x64 = ((f0.x + f0.y) + (f0.z + f0.w)) + ((f1.x + f1.y) + (f1.z + f1.w));
      float m = x;
      m = fmaxf(m, dpp_xor1(m));
      m = fmaxf(m, dpp_xor2(m));
      m = fmaxf(m, __shfl_xor(m, 4));
      m = fmaxf(m, dpp_xor8(m));
      m = fmaxf(m, __shfl_xor(m, 16));
      m = fmaxf(m, __shfl_xor(m, 32));
      m = fmaxf(m, x64);
      const float p = __expf(x - m);
      const float p64 = __expf(x64 - m);
      float ss = p;
      ss += dpp_xor1(ss);
      ss += dpp_xor2(ss);
      ss += __shfl_xor(ss, 4);
      ss += dpp_xor8(ss);
      ss += __shfl_xor(ss, 16);
      ss += __shfl_xor(ss, 32);
      ss += p64;
      const float inv = 1.0f / ss;
      sct[i * 66 + l] = p * inv;
      if (l == 0) sct[i * 66 + 64] = p64 * inv;
    }
    __syncthreads();

    // s-pass: lane l holds row-l scores in regs; per-row broadcast via readlane.
    float sc[8], c64[8];
#pragma unroll
    for (int i = 0; i < 8; ++i) sc[i] = sct[i * 66 + l];
#pragma unroll
    for (int i = 0; i < 8; ++i) c64[i] = sct[i * 66 + 64];

    float2 s2[8];
#pragma unroll
    for (int i = 0; i < 8; ++i) s2[i] = make_float2(0.f, 0.f);
#pragma unroll
    for (int r = 0; r < 16; ++r) {
      const int n = 16 * w + r;  // wave-uniform
#pragma unroll
      for (int i = 0; i < 8; ++i) {
        const float cwv = readlane_f(sc[i], n);
        s2[i].x = fmaf(cwv, q2[r].x, s2[i].x);
        s2[i].y = fmaf(cwv, q2[r].y, s2[i].y);
      }
    }
    if (w == 0) {
#pragma unroll
      for (int i = 0; i < 8; ++i) {
        s2[i].x = fmaf(c64[i], v2.x, s2[i].x);
        s2[i].y = fmaf(c64[i], v2.y, s2[i].y);
      }
    }
#pragma unroll
    for (int i = 0; i < 8; ++i)
      *(float2*)&smem[w * 1024 + i * 128 + 2 * l] = s2[i];  // spart overlays epart
    __syncthreads();
    float4 acc = make_float4(0.f, 0.f, 0.f, 0.f);
#pragma unroll
    for (int w4 = 0; w4 < 4; ++w4) {
      const float4 pp = *(const float4*)&smem[w4 * 1024 + t * 4];
      acc.x += pp.x; acc.y += pp.y; acc.z += pp.z; acc.w += pp.w;
    }
    *(float4*)(U + (size_t)b * 1024 + t * 4) = acc;
    __syncthreads();  // protect smem overlay before next batch's e-pass
  }
}

// ---- gemm_out: 512 blocks = 128 row-tiles(64) x 4 kc(256). Thread tile 4x8.
// S^T staged stride 68 floats = 272B = 17*16B -> ds_read_b128 truly aligned.
__global__ __launch_bounds__(256) void gemm_out_k(
    const float* __restrict__ S, const float* __restrict__ Z,
    float* __restrict__ P0, float* __restrict__ PW) {
  __shared__ float STl[64 * 68];
  const int rb = blockIdx.x >> 2;  // 128 row-tiles of 64
  const int kc = blockIdx.x & 3;   // 4 k-chunks of 256
  const int t = threadIdx.x;
  const int rg = t >> 4;           // 16 groups x 4 rows
  const int cg = t & 15;           // 16 groups x 8 cols
  float4 acc[4][2];
#pragma unroll
  for (int r = 0; r < 4; ++r) {
    acc[r][0] = make_float4(0.f, 0.f, 0.f, 0.f);
    acc[r][1] = make_float4(0.f, 0.f, 0.f, 0.f);
  }
  for (int sub = 0; sub < 4; ++sub) {
    const int kb = kc * 256 + sub * 64;
    __syncthreads();
#pragma unroll
    for (int j = 0; j < 4; ++j) {
      const int i4 = t + j * 256;          // 0..1023 float4s
      const int row = i4 >> 4, kq = i4 & 15;
      const float4 s4 = *(const float4*)&S[(size_t)(rb * 64 + row) * 1024 + kb + kq * 4];
      STl[(kq * 4 + 0) * 68 + row] = s4.x;
      STl[(kq * 4 + 1) * 68 + row] = s4.y;
      STl[(kq * 4 + 2) * 68 + row] = s4.z;
      STl[(kq * 4 + 3) * 68 + row] = s4.w;
    }
    __syncthreads();
#pragma unroll 4
    for (int k = 0; k < 64; ++k) {
      const float4 sa = *(const float4*)&STl[k * 68 + rg * 4];
      const float* zr = Z + (size_t)(kb + k) * 128 + cg * 8;
      const float4 za = *(const float4*)zr;
      const float4 zb = *(const float4*)(zr + 4);
      const float sr[4] = {sa.x, sa.y, sa.z, sa.w};
#pragma unroll
      for (int r = 0; r < 4; ++r) {
        acc[r][0].x = fmaf(sr[r], za.x, acc[r][0].x);
        acc[r][0].y = fmaf(sr[r], za.y, acc[r][0].y);
        acc[r][0].z = fmaf(sr[r], za.z, acc[r][0].z);
        acc[r][0].w = fmaf(sr[r], za.w, acc[r][0].w);
        acc[r][1].x = fmaf(sr[r], zb.x, acc[r][1].x);
        acc[r][1].y = fmaf(sr[r], zb.y, acc[r][1].y);
        acc[r][1].z = fmaf(sr[r], zb.z, acc[r][1].z);
        acc[r][1].w = fmaf(sr[r], zb.w, acc[r][1].w);
      }
    }
  }
  float* P = (kc == 0) ? P0 : (PW + (size_t)(kc - 1) * 1048576);
#pragma unroll
  for (int r = 0; r < 4; ++r) {
    float* prow = P + (size_t)(rb * 64 + rg * 4 + r) * 128 + cg * 8;
    *(float4*)(prow + 0) = acc[r][0];
    *(float4*)(prow + 4) = acc[r][1];
  }
}

// ---- reduce 4 partials + z0, relu, write d_out. 1024 blocks x 256 (float4).
__global__ __launch_bounds__(256) void reduce_relu_k(
    float* __restrict__ out, const float* __restrict__ PW,
    const float* __restrict__ z0) {
  const int idx = blockIdx.x * 256 + threadIdx.x;
  const float4 z4 = *(const float4*)&z0[(idx & 31) * 4];
  float4 a = ((const float4*)out)[idx];
  const float4 p1 = ((const float4*)(PW + 0 * 1048576))[idx];
  const float4 p2 = ((const float4*)(PW + 1 * 1048576))[idx];
  const float4 p3 = ((const float4*)(PW + 2 * 1048576))[idx];
  a.x = fmaxf(a.x + p1.x + p2.x + p3.x + z4.x, 0.f);
  a.y = fmaxf(a.y + p1.y + p2.y + p3.y + z4.y, 0.f);
  a.z = fmaxf(a.z + p1.z + p2.z + p3.z + z4.z, 0.f);
  a.w = fmaxf(a.w + p1.w + p2.w + p3.w + z4.w, 0.f);
  ((float4*)out)[idx] = a;
}

extern "C" void kernel_launch(void* const* d_in, const int* in_sizes, int n_in,
                              void* d_out, int out_size, void* d_ws, size_t ws_size,
                              hipStream_t stream) {
  const float* query = (const float*)d_in[0];
  const float* value = (const float*)d_in[1];
  const float* Wa    = (const float*)d_in[2];
  const float* ba    = (const float*)d_in[3];
  const float* Wo    = (const float*)d_in[4];
  const float* bo    = (const float*)d_in[5];
  float* ws = (float*)d_ws;
  float* P  = ws + WS_P;
  float* Q0 = ws + WS_Q0;
  float* Q1 = ws + WS_Q1;
  float* R  = ws + WS_R;
  float* WT = ws + WS_WT;
  float* WU = ws + WS_WU;
  float* ZT = ws + WS_ZT;
  float* Z0 = ws + WS_Z0;
  float* U  = ws + WS_U;
  float* PW = ws + WS_PO;

  // K1: pair products P_j = Wa_{2j} @ Wa_{2j+1} + bias chain/z0
  MMArgs a1{};
  for (int j = 0; j < 4; ++j)
    a1.j[j] = MMJob{Wa + 2 * j * 16384, Wa + (2 * j + 1) * 16384, P + j * 16384, nullptr};
  k1_setup<<<17, 256, 0, stream>>>(a1, Wa, ba, Wo, bo, Z0);

  // K2: Q0 = P0@P1 (Wa0..3), Q1 = P2@P3 (Wa4..7), R = P2@Wa6
  MMArgs a2{};
  a2.j[0] = MMJob{P, P + 16384, Q0, nullptr};
  a2.j[1] = MMJob{P + 2 * 16384, P + 3 * 16384, Q1, nullptr};
  a2.j[2] = MMJob{P + 2 * 16384, Wa + 6 * 16384, R, nullptr};
  mm128_jobs<<<12, 256, 0, stream>>>(a2);

  // K3: all prefixes W~_i (+ transposed store into WU)
  MMArgs a3{};
  a3.j[0] = MMJob{nullptr, Wa,             WT + 0 * 16384, WU + 0 * 128};
  a3.j[1] = MMJob{nullptr, P,              WT + 1 * 16384, WU + 1 * 128};
  a3.j[2] = MMJob{P,       Wa + 2 * 16384, WT + 2 * 16384, WU + 2 * 128};
  a3.j[3] = MMJob{nullptr, Q0,             WT + 3 * 16384, WU + 3 * 128};
  a3.j[4] = MMJob{Q0,      Wa + 4 * 16384, WT + 4 * 16384, WU + 4 * 128};
  a3.j[5] = MMJob{Q0,      P + 2 * 16384,  WT + 5 * 16384, WU + 5 * 128};
  a3.j[6] = MMJob{Q0,      R,              WT + 6 * 16384, WU + 6 * 128};
  a3.j[7] = MMJob{Q0,      Q1,             WT + 7 * 16384, WU + 7 * 128};
  mm128_jobs<<<32, 256, 0, stream>>>(a3);

  // K4: Z (plain M_i = W~_i @ Wo_i) + gemm_U
  MMArgs a4{};
  for (int i = 0; i < 8; ++i)
    a4.j[i] = MMJob{WT + i * 16384, Wo + i * 16384, ZT + i * 16384, nullptr};
  k4_combo<<<544, 256, 0, stream>>>(a4, value, WU, U);

  // K5: fused e/softmax/s — 4 batches/block, grid 2048
  attn_main_k<<<8192 / ATTN_NB, 256, 0, stream>>>(query, value, U);

  // K6: k-split-4 gemm_out (aligned stride-68 staging); K7: reduce + z0 + relu
  gemm_out_k<<<512, 256, 0, stream>>>(U, ZT, (float*)d_out, PW);
  reduce_relu_k<<<1024, 256, 0, stream>>>((float*)d_out, PW, Z0);
}

// Round 9
// 220.195 us; speedup vs baseline: 1.2036x; 1.2036x over previous
//
#include <hip/hip_runtime.h>
#include <math.h>

// ---------------- workspace layout (float offsets) ----------------
#define WS_P  0         // P[4][128*128]  pair products
#define WS_Q0 65536     // Wa0..3 product
#define WS_Q1 81920     // Wa4..7 product
#define WS_R  98304     // Wa4*Wa5*Wa6
#define WS_WT 114688    // W~[8][128*128]
#define WS_WU 245760    // WU[k][i*128+h] = W~_i[h][k]   (128 x 1024)
#define WS_ZT 376832    // Z[c*128 + k'] = M_i[h][k'], c=i*128+h  (1024 x 128)
#define WS_Z0 507904    // z0[128]
#define WS_U  524288    // U/S [8192][1024]  (u then overwritten by s)
#define WS_PO 8912896   // partials kc=1..3: 3 x 8192x128

struct MMJob { const float* A; const float* B; float* C; float* wu; };
struct MMArgs { MMJob j[8]; };

// ---- DPP cross-lane (VALU pipe, not DS): xor1/xor2 = quad_perm, xor8 = row_ror:8
__device__ __forceinline__ float dpp_xor1(float x) {
  return __int_as_float(__builtin_amdgcn_update_dpp(0, __float_as_int(x), 0xB1, 0xF, 0xF, false));
}
__device__ __forceinline__ float dpp_xor2(float x) {
  return __int_as_float(__builtin_amdgcn_update_dpp(0, __float_as_int(x), 0x4E, 0xF, 0xF, false));
}
__device__ __forceinline__ float dpp_xor8(float x) {
  return __int_as_float(__builtin_amdgcn_update_dpp(0, __float_as_int(x), 0x128, 0xF, 0xF, false));
}
__device__ __forceinline__ float readlane_f(float v, int n) {
  return __int_as_float(__builtin_amdgcn_readlane(__float_as_int(v), n));
}

// ---- 128x128 matmul job (C = A@B; A==nullptr -> copy B). wu = transposed store.
__device__ void mm128_job(const MMJob J, const int tile, const int t, float* Al) {
  const int col = t & 127;
  const int rg = t >> 7;
  if (J.A == nullptr) {
    for (int rr = 0; rr < 16; ++rr) {
      const int r = tile * 32 + rg * 16 + rr;
      const float v = J.B[r * 128 + col];
      if (J.C) J.C[r * 128 + col] = v;
      if (J.wu) J.wu[col * 1024 + r] = v;
    }
    return;
  }
  for (int jj = 0; jj < 16; ++jj) {
    const int idx = t + jj * 256;
    Al[idx] = J.A[tile * 32 * 128 + idx];
  }
  __syncthreads();
  float acc[16];
#pragma unroll
  for (int rr = 0; rr < 16; ++rr) acc[rr] = 0.f;
  for (int h = 0; h < 128; ++h) {
    const float bv = J.B[h * 128 + col];
#pragma unroll
    for (int rr = 0; rr < 16; ++rr)
      acc[rr] = fmaf(Al[(rg * 16 + rr) * 128 + h], bv, acc[rr]);
  }
#pragma unroll
  for (int rr = 0; rr < 16; ++rr) {
    const int r = tile * 32 + rg * 16 + rr;
    if (J.C) J.C[r * 128 + col] = acc[rr];
    if (J.wu) J.wu[col * 1024 + r] = acc[rr];
  }
}

__global__ __launch_bounds__(256) void mm128_jobs(MMArgs args) {
  __shared__ float smem[4096];
  mm128_job(args.j[blockIdx.x >> 2], blockIdx.x & 3, threadIdx.x, smem);
}

// ---- bias chain + z0 (one block; overlapped inside k4_combo)
__device__ void bias_z0_dev(const float* __restrict__ Wa, const float* __restrict__ ba,
                            const float* __restrict__ Wo, const float* __restrict__ bo,
                            float* __restrict__ z0, const int t, float* smem) {
  float* bt = smem;            // [8][128]
  float* zpart = smem + 1024;  // [2][128]
  if (t < 128) bt[t] = ba[t];
  __syncthreads();
  for (int i = 1; i < 8; ++i) {
    if (t < 128) {
      float v = ba[i * 128 + t];
      for (int h = 0; h < 128; ++h)
        v = fmaf(bt[(i - 1) * 128 + h], Wa[i * 16384 + h * 128 + t], v);
      bt[i * 128 + t] = v;
    }
    __syncthreads();
  }
  const int col = t & 127, half = t >> 7;
  float z = half ? 0.f : bo[col];
  for (int i = half * 4; i < half * 4 + 4; ++i)
    for (int h = 0; h < 128; ++h)
      z = fmaf(bt[i * 128 + h], Wo[(i * 128 + h) * 128 + col], z);
  zpart[half * 128 + col] = z;
  __syncthreads();
  if (t < 128) z0[t] = zpart[t] + zpart[128 + t];
}

// ---- gemm_U: U[b][c] = sum_k V[b][k] WU[k][c]; 128 rows x 128 cols per block
__device__ void gemm_U_dev(const float* __restrict__ V, const float* __restrict__ WU,
                           float* __restrict__ U, const int bid, const int t, float* Vl) {
  const int rt = bid >> 3;
  const int ct = bid & 7;
  const int cg = t & 7;
  const int rg = t >> 3;
  const int r0 = rt * 128;
  float4 acc[4][4];
#pragma unroll
  for (int a = 0; a < 4; ++a)
#pragma unroll
    for (int c = 0; c < 4; ++c) acc[a][c] = make_float4(0.f, 0.f, 0.f, 0.f);
  for (int kc = 0; kc < 4; ++kc) {
    __syncthreads();
    {
      const int srow = t >> 3, k8 = t & 7;
#pragma unroll
      for (int pp = 0; pp < 4; ++pp) {
        const int rr = pp * 32 + srow;
        *(float4*)&Vl[rr * 33 + k8 * 4] =
            *(const float4*)&V[(size_t)(r0 + rr) * 128 + kc * 32 + k8 * 4];
      }
    }
    __syncthreads();
#pragma unroll 4
    for (int kk = 0; kk < 32; ++kk) {
      const float* wrow = WU + (size_t)(kc * 32 + kk) * 1024 + ct * 128 + cg * 16;
      const float4 w0 = *(const float4*)(wrow + 0);
      const float4 w1 = *(const float4*)(wrow + 4);
      const float4 w2 = *(const float4*)(wrow + 8);
      const float4 w3 = *(const float4*)(wrow + 12);
#pragma unroll
      for (int r = 0; r < 4; ++r) {
        const float s = Vl[(rg * 4 + r) * 33 + kk];
        acc[r][0].x = fmaf(s, w0.x, acc[r][0].x); acc[r][0].y = fmaf(s, w0.y, acc[r][0].y);
        acc[r][0].z = fmaf(s, w0.z, acc[r][0].z); acc[r][0].w = fmaf(s, w0.w, acc[r][0].w);
        acc[r][1].x = fmaf(s, w1.x, acc[r][1].x); acc[r][1].y = fmaf(s, w1.y, acc[r][1].y);
        acc[r][1].z = fmaf(s, w1.z, acc[r][1].z); acc[r][1].w = fmaf(s, w1.w, acc[r][1].w);
        acc[r][2].x = fmaf(s, w2.x, acc[r][2].x); acc[r][2].y = fmaf(s, w2.y, acc[r][2].y);
        acc[r][2].z = fmaf(s, w2.z, acc[r][2].z); acc[r][2].w = fmaf(s, w2.w, acc[r][2].w);
        acc[r][3].x = fmaf(s, w3.x, acc[r][3].x); acc[r][3].y = fmaf(s, w3.y, acc[r][3].y);
        acc[r][3].z = fmaf(s, w3.z, acc[r][3].z); acc[r][3].w = fmaf(s, w3.w, acc[r][3].w);
      }
    }
  }
#pragma unroll
  for (int r = 0; r < 4; ++r) {
    float* urow = U + (size_t)(r0 + rg * 4 + r) * 1024 + ct * 128 + cg * 16;
    *(float4*)(urow + 0) = acc[r][0];
    *(float4*)(urow + 4) = acc[r][1];
    *(float4*)(urow + 8) = acc[r][2];
    *(float4*)(urow + 12) = acc[r][3];
  }
}

// ---- K4: ZT jobs (0..31) + gemm_U (32..543) + bias/z0 (544)
__global__ __launch_bounds__(256) void k4_combo(MMArgs args,
    const float* __restrict__ V, const float* __restrict__ WU, float* __restrict__ U,
    const float* __restrict__ Wa, const float* __restrict__ ba,
    const float* __restrict__ Wo, const float* __restrict__ bo,
    float* __restrict__ z0) {
  __shared__ float smem[4224];
  const int bid = blockIdx.x;
  if (bid < 32) mm128_job(args.j[bid >> 2], bid & 3, threadIdx.x, smem);
  else if (bid < 544) gemm_U_dev(V, WU, U, bid - 32, threadIdx.x, smem);
  else bias_z0_dev(Wa, ba, Wo, bo, z0, threadIdx.x, smem);
}

// ---- attn: 1 batch/block (R7 grid), sigma-permuted u-load -> select-free
// DPP butterfly. u2[j] holds head (myhead^j); fold partner at xor1 holds
// (myhead^4)^(i^4) = myhead^i, so a4[i] = p[i] + dpp_xor1(p[i+4]) needs no
// cndmask. Final folded value is head `myhead`, same ebase write as before.
__global__ __launch_bounds__(256, 4) void attn_main_k(
    const float* __restrict__ query, const float* __restrict__ value,
    float* __restrict__ U) {
  __shared__ float smem[4948];   // epart 65*68=4420 (spart[4][1024] overlays) + sct 8*66
  float* sct = smem + 4420;
  const int b = blockIdx.x;
  const int t = threadIdx.x;
  const int w = t >> 6;
  const int l = t & 63;

  const int sel1 = l & 1, sel2 = (l >> 1) & 1, sel8 = (l >> 3) & 1;
  const int g = ((l >> 2) & 1) | (((l >> 4) & 1) << 1) | (((l >> 5) & 1) << 2);
  const int myhead = 4 * sel1 + 2 * sel2 + sel8;
  const int ebase = myhead * 8 + g;  // 0..63, bijective over lanes

  // sigma-permuted u load: u2[j] = U[b, (myhead^j)*128 + 2l .. +1]
  float2 u2[8];
  {
    const float* ub = U + (size_t)b * 1024 + 2 * l;
#pragma unroll
    for (int jj = 0; jj < 8; ++jj) u2[jj] = *(const float2*)(ub + ((myhead ^ jj) << 7));
  }
  float2 q2[16];
  {
    const float* qb = query + (size_t)b * 8192 + (size_t)(w * 16) * 128 + 2 * l;
#pragma unroll
    for (int r = 0; r < 16; ++r) q2[r] = *(const float2*)(qb + r * 128);
  }
  const float2 v2 = *(const float2*)(value + (size_t)b * 128 + 2 * l);

  auto epass = [&](const float2 qv, const int n) {
    float p[8];
#pragma unroll
    for (int i = 0; i < 8; ++i) p[i] = fmaf(qv.y, u2[i].y, qv.x * u2[i].x);
    float a4[4];
#pragma unroll
    for (int i = 0; i < 4; ++i) a4[i] = p[i] + dpp_xor1(p[i + 4]);
    float a2v[2];
#pragma unroll
    for (int i = 0; i < 2; ++i) a2v[i] = a4[i] + dpp_xor2(a4[i + 2]);
    smem[n * 68 + ebase] = a2v[0] + dpp_xor8(a2v[1]);
  };
#pragma unroll
  for (int r = 0; r < 16; ++r) epass(q2[r], 16 * w + r);
  if (w == 0) epass(v2, 64);
  __syncthreads();

  // softmax: wave w -> heads 2w, 2w+1; lane l -> row n=l; sums 8 g-partials.
#pragma unroll
  for (int ii = 0; ii < 2; ++ii) {
    const int i = 2 * w + ii;
    const float4 e0 = *(const float4*)&smem[l * 68 + i * 8];
    const float4 e1 = *(const float4*)&smem[l * 68 + i * 8 + 4];
    const float4 f0 = *(const float4*)&smem[64 * 68 + i * 8];
    const float4 f1 = *(const float4*)&smem[64 * 68 + i * 8 + 4];
    const float x = ((e0.x + e0.y) + (e0.z + e0.w)) + ((e1.x + e1.y) + (e1.z + e1.w));
    const float x64 = ((f0.x + f0.y) + (f0.z + f0.w)) + ((f1.x + f1.y) + (f1.z + f1.w));
    float m = x;
    m = fmaxf(m, dpp_xor1(m));
    m = fmaxf(m, dpp_xor2(m));
    m = fmaxf(m, __shfl_xor(m, 4));
    m = fmaxf(m, dpp_xor8(m));
    m = fmaxf(m, __shfl_xor(m, 16));
    m = fmaxf(m, __shfl_xor(m, 32));
    m = fmaxf(m, x64);
    const float p = __expf(x - m);
    const float p64 = __expf(x64 - m);
    float ss = p;
    ss += dpp_xor1(ss);
    ss += dpp_xor2(ss);
    ss += __shfl_xor(ss, 4);
    ss += dpp_xor8(ss);
    ss += __shfl_xor(ss, 16);
    ss += __shfl_xor(ss, 32);
    ss += p64;
    const float inv = 1.0f / ss;
    sct[i * 66 + l] = p * inv;
    if (l == 0) sct[i * 66 + 64] = p64 * inv;
  }
  __syncthreads();

  // s-pass: lane l holds row-l scores in regs; per-row broadcast via readlane.
  float sc[8], c64[8];
#pragma unroll
  for (int i = 0; i < 8; ++i) sc[i] = sct[i * 66 + l];
#pragma unroll
  for (int i = 0; i < 8; ++i) c64[i] = sct[i * 66 + 64];

  float2 s2[8];
#pragma unroll
  for (int i = 0; i < 8; ++i) s2[i] = make_float2(0.f, 0.f);
#pragma unroll
  for (int r = 0; r < 16; ++r) {
    const int n = 16 * w + r;  // wave-uniform
#pragma unroll
    for (int i = 0; i < 8; ++i) {
      const float cwv = readlane_f(sc[i], n);
      s2[i].x = fmaf(cwv, q2[r].x, s2[i].x);
      s2[i].y = fmaf(cwv, q2[r].y, s2[i].y);
    }
  }
  if (w == 0) {
#pragma unroll
    for (int i = 0; i < 8; ++i) {
      s2[i].x = fmaf(c64[i], v2.x, s2[i].x);
      s2[i].y = fmaf(c64[i], v2.y, s2[i].y);
    }
  }
#pragma unroll
  for (int i = 0; i < 8; ++i)
    *(float2*)&smem[w * 1024 + i * 128 + 2 * l] = s2[i];  // spart overlays epart
  __syncthreads();
  float4 acc = make_float4(0.f, 0.f, 0.f, 0.f);
#pragma unroll
  for (int w4 = 0; w4 < 4; ++w4) {
    const float4 pp = *(const float4*)&smem[w4 * 1024 + t * 4];
    acc.x += pp.x; acc.y += pp.y; acc.z += pp.z; acc.w += pp.w;
  }
  *(float4*)(U + (size_t)b * 1024 + t * 4) = acc;
}

// ---- gemm_out: 512 blocks = 128 row-tiles(64) x 4 kc(256). Thread tile 4x8.
// S^T staged stride 68 floats = 272B = 17*16B -> ds_read_b128 truly aligned.
__global__ __launch_bounds__(256) void gemm_out_k(
    const float* __restrict__ S, const float* __restrict__ Z,
    float* __restrict__ P0, float* __restrict__ PW) {
  __shared__ float STl[64 * 68];
  const int rb = blockIdx.x >> 2;  // 128 row-tiles of 64
  const int kc = blockIdx.x & 3;   // 4 k-chunks of 256
  const int t = threadIdx.x;
  const int rg = t >> 4;           // 16 groups x 4 rows
  const int cg = t & 15;           // 16 groups x 8 cols
  float4 acc[4][2];
#pragma unroll
  for (int r = 0; r < 4; ++r) {
    acc[r][0] = make_float4(0.f, 0.f, 0.f, 0.f);
    acc[r][1] = make_float4(0.f, 0.f, 0.f, 0.f);
  }
  for (int sub = 0; sub < 4; ++sub) {
    const int kb = kc * 256 + sub * 64;
    __syncthreads();
#pragma unroll
    for (int j = 0; j < 4; ++j) {
      const int i4 = t + j * 256;          // 0..1023 float4s
      const int row = i4 >> 4, kq = i4 & 15;
      const float4 s4 = *(const float4*)&S[(size_t)(rb * 64 + row) * 1024 + kb + kq * 4];
      STl[(kq * 4 + 0) * 68 + row] = s4.x;
      STl[(kq * 4 + 1) * 68 + row] = s4.y;
      STl[(kq * 4 + 2) * 68 + row] = s4.z;
      STl[(kq * 4 + 3) * 68 + row] = s4.w;
    }
    __syncthreads();
#pragma unroll 4
    for (int k = 0; k < 64; ++k) {
      const float4 sa = *(const float4*)&STl[k * 68 + rg * 4];
      const float* zr = Z + (size_t)(kb + k) * 128 + cg * 8;
      const float4 za = *(const float4*)zr;
      const float4 zb = *(const float4*)(zr + 4);
      const float sr[4] = {sa.x, sa.y, sa.z, sa.w};
#pragma unroll
      for (int r = 0; r < 4; ++r) {
        acc[r][0].x = fmaf(sr[r], za.x, acc[r][0].x);
        acc[r][0].y = fmaf(sr[r], za.y, acc[r][0].y);
        acc[r][0].z = fmaf(sr[r], za.z, acc[r][0].z);
        acc[r][0].w = fmaf(sr[r], za.w, acc[r][0].w);
        acc[r][1].x = fmaf(sr[r], zb.x, acc[r][1].x);
        acc[r][1].y = fmaf(sr[r], zb.y, acc[r][1].y);
        acc[r][1].z = fmaf(sr[r], zb.z, acc[r][1].z);
        acc[r][1].w = fmaf(sr[r], zb.w, acc[r][1].w);
      }
    }
  }
  float* P = (kc == 0) ? P0 : (PW + (size_t)(kc - 1) * 1048576);
#pragma unroll
  for (int r = 0; r < 4; ++r) {
    float* prow = P + (size_t)(rb * 64 + rg * 4 + r) * 128 + cg * 8;
    *(float4*)(prow + 0) = acc[r][0];
    *(float4*)(prow + 4) = acc[r][1];
  }
}

// ---- reduce 4 partials + z0, relu, write d_out. 1024 blocks x 256 (float4).
__global__ __launch_bounds__(256) void reduce_relu_k(
    float* __restrict__ out, const float* __restrict__ PW,
    const float* __restrict__ z0) {
  const int idx = blockIdx.x * 256 + threadIdx.x;
  const float4 z4 = *(const float4*)&z0[(idx & 31) * 4];
  float4 a = ((const float4*)out)[idx];
  const float4 p1 = ((const float4*)(PW + 0 * 1048576))[idx];
  const float4 p2 = ((const float4*)(PW + 1 * 1048576))[idx];
  const float4 p3 = ((const float4*)(PW + 2 * 1048576))[idx];
  a.x = fmaxf(a.x + p1.x + p2.x + p3.x + z4.x, 0.f);
  a.y = fmaxf(a.y + p1.y + p2.y + p3.y + z4.y, 0.f);
  a.z = fmaxf(a.z + p1.z + p2.z + p3.z + z4.z, 0.f);
  a.w = fmaxf(a.w + p1.w + p2.w + p3.w + z4.w, 0.f);
  ((float4*)out)[idx] = a;
}

extern "C" void kernel_launch(void* const* d_in, const int* in_sizes, int n_in,
                              void* d_out, int out_size, void* d_ws, size_t ws_size,
                              hipStream_t stream) {
  const float* query = (const float*)d_in[0];
  const float* value = (const float*)d_in[1];
  const float* Wa    = (const float*)d_in[2];
  const float* ba    = (const float*)d_in[3];
  const float* Wo    = (const float*)d_in[4];
  const float* bo    = (const float*)d_in[5];
  float* ws = (float*)d_ws;
  float* P  = ws + WS_P;
  float* Q0 = ws + WS_Q0;
  float* Q1 = ws + WS_Q1;
  float* R  = ws + WS_R;
  float* WT = ws + WS_WT;
  float* WU = ws + WS_WU;
  float* ZT = ws + WS_ZT;
  float* Z0 = ws + WS_Z0;
  float* U  = ws + WS_U;
  float* PW = ws + WS_PO;

  // K1: pair products P_j = Wa_{2j} @ Wa_{2j+1}  (bias chain moved to K4)
  MMArgs a1{};
  for (int j = 0; j < 4; ++j)
    a1.j[j] = MMJob{Wa + 2 * j * 16384, Wa + (2 * j + 1) * 16384, P + j * 16384, nullptr};
  mm128_jobs<<<16, 256, 0, stream>>>(a1);

  // K2: Q0 = P0@P1 (Wa0..3), Q1 = P2@P3 (Wa4..7), R = P2@Wa6
  MMArgs a2{};
  a2.j[0] = MMJob{P, P + 16384, Q0, nullptr};
  a2.j[1] = MMJob{P + 2 * 16384, P + 3 * 16384, Q1, nullptr};
  a2.j[2] = MMJob{P + 2 * 16384, Wa + 6 * 16384, R, nullptr};
  mm128_jobs<<<12, 256, 0, stream>>>(a2);

  // K3: all prefixes W~_i (+ transposed store into WU)
  MMArgs a3{};
  a3.j[0] = MMJob{nullptr, Wa,             WT + 0 * 16384, WU + 0 * 128};
  a3.j[1] = MMJob{nullptr, P,              WT + 1 * 16384, WU + 1 * 128};
  a3.j[2] = MMJob{P,       Wa + 2 * 16384, WT + 2 * 16384, WU + 2 * 128};
  a3.j[3] = MMJob{nullptr, Q0,             WT + 3 * 16384, WU + 3 * 128};
  a3.j[4] = MMJob{Q0,      Wa + 4 * 16384, WT + 4 * 16384, WU + 4 * 128};
  a3.j[5] = MMJob{Q0,      P + 2 * 16384,  WT + 5 * 16384, WU + 5 * 128};
  a3.j[6] = MMJob{Q0,      R,              WT + 6 * 16384, WU + 6 * 128};
  a3.j[7] = MMJob{Q0,      Q1,             WT + 7 * 16384, WU + 7 * 128};
  mm128_jobs<<<32, 256, 0, stream>>>(a3);

  // K4: Z (M_i = W~_i @ Wo_i) + gemm_U + bias/z0 (block 544, overlapped)
  MMArgs a4{};
  for (int i = 0; i < 8; ++i)
    a4.j[i] = MMJob{WT + i * 16384, Wo + i * 16384, ZT + i * 16384, nullptr};
  k4_combo<<<545, 256, 0, stream>>>(a4, value, WU, U, Wa, ba, Wo, bo, Z0);

  // K5: fused e/softmax/s — 1 batch/block (R7 grid), sigma-permuted u-load
  attn_main_k<<<8192, 256, 0, stream>>>(query, value, U);

  // K6: k-split-4 gemm_out (aligned stride-68 staging); K7: reduce + z0 + relu
  gemm_out_k<<<512, 256, 0, stream>>>(U, ZT, (float*)d_out, PW);
  reduce_relu_k<<<1024, 256, 0, stream>>>((float*)d_out, PW, Z0);
}